// Round 3
// baseline (1236.518 us; speedup 1.0000x reference)
//
#include <hip/hip_runtime.h>

// Causal self-attention, B=2 S=2048 D=2048 H=16 DK=128.
// d_out = [out: 4096*2048 f32][attn: 2*16*2048*2048 f32]
// ws (bf16): qb,kb [B,H,S,DK], vT [B,H,DK,S], xb [B,S,D], qf,kf,vf [B,S,D],
//            wq,wk,wv,wo [D,D], then sums f32 [B*H*S].  ~151.3 MB total.
// Pipeline: cvt -> fused QKV proj -> scores(exp + atomic row-sums, triangular
//           grid) -> PV(normalize attn in-place + zero-fill + P@V) -> out proj.
// Softmax kernel eliminated: no max-subtraction (S*scale ~ N(0,1); exp overflow
// would need ~88 sigma), row sums via device-scope atomics.

#define BATCH 2
#define S_LEN 2048
#define D_DIM 2048
#define H_NUM 16
#define DKD   128
#define NEL   ((size_t)BATCH * S_LEN * D_DIM)   // 8388608
#define NWL   ((size_t)D_DIM * D_DIM)           // 4194304

typedef __attribute__((ext_vector_type(8))) short  short8;
typedef __attribute__((ext_vector_type(4))) short  short4v;
typedef __attribute__((ext_vector_type(4))) float  floatx4;

__device__ __forceinline__ unsigned short f2bf(float f) {
    unsigned int u = __float_as_uint(f);
    u += 0x7fffu + ((u >> 16) & 1u);   // round-to-nearest-even
    return (unsigned short)(u >> 16);
}

__device__ __forceinline__ void gload16(const void* g, void* l) {
    __builtin_amdgcn_global_load_lds(
        (const __attribute__((address_space(1))) void*)g,
        (__attribute__((address_space(3))) void*)l, 16, 0, 0);
}

// 128(row) x 32(k) bf16 tile -> LDS [128][32] via global_load_lds width=16.
// Dest = wave-uniform base + lane*16 (HW requirement) -- layout is linear.
__device__ __forceinline__ void stage_lds_bf16(const unsigned short* __restrict__ src,
                                               int ld, int row0, int k0,
                                               unsigned short* __restrict__ dst,
                                               int tid) {
    #pragma unroll
    for (int j = 0; j < 2; ++j) {
        const int c = tid + j * 256;          // 512 chunks of 8 bf16 (16 B)
        const int r = c >> 2, kc = (c & 3) * 8;
        gload16(src + (size_t)(row0 + r) * ld + k0 + kc, dst + c * 8);
    }
}

// ---------------- fused QKV projection: z in {0,1,2} selects q/k/v ----------
__launch_bounds__(256)
__global__ void proj_qkv(const unsigned short* __restrict__ xf,   // qf base
                         const unsigned short* __restrict__ wb,   // wq base
                         const float* __restrict__ bq, const float* __restrict__ bk,
                         const float* __restrict__ bv,
                         unsigned short* __restrict__ ob) {       // qb base
    const int z = blockIdx.z;
    const unsigned short* Ap = xf + (size_t)z * NEL;
    const unsigned short* Bp = wb + (size_t)z * NWL;
    const float* bias = (z == 0) ? bq : (z == 1) ? bk : bv;
    const int m0 = blockIdx.y * 128, n0 = blockIdx.x * 128;

    __shared__ __align__(16) unsigned short As[128][32];
    __shared__ __align__(16) unsigned short Bs[128][32];
    const int tid = threadIdx.x, lane = tid & 63, wave = tid >> 6;
    const int quad = lane >> 4, l16 = lane & 15;
    const int mw = (wave >> 1) * 64, nw = (wave & 1) * 64;

    floatx4 acc[4][4];
    #pragma unroll
    for (int i = 0; i < 4; ++i)
        #pragma unroll
        for (int j = 0; j < 4; ++j) acc[i][j] = (floatx4){0.f, 0.f, 0.f, 0.f};

    for (int k0 = 0; k0 < D_DIM; k0 += 32) {
        if (k0 > 0) __syncthreads();
        stage_lds_bf16(Bp, D_DIM, n0, k0, &Bs[0][0], tid);
        stage_lds_bf16(Ap, D_DIM, m0, k0, &As[0][0], tid);
        __syncthreads();
        short8 af[4], bf[4];
        #pragma unroll
        for (int i = 0; i < 4; ++i) af[i] = *(const short8*)&As[mw + i*16 + l16][quad*8];
        #pragma unroll
        for (int j = 0; j < 4; ++j) bf[j] = *(const short8*)&Bs[nw + j*16 + l16][quad*8];
        #pragma unroll
        for (int i = 0; i < 4; ++i)
            #pragma unroll
            for (int j = 0; j < 4; ++j)
                acc[i][j] = __builtin_amdgcn_mfma_f32_16x16x32_bf16(
                    af[i], bf[j], acc[i][j], 0, 0, 0);
    }

    #pragma unroll
    for (int i = 0; i < 4; ++i)
        #pragma unroll
        for (int j = 0; j < 4; ++j)
            #pragma unroll
            for (int r = 0; r < 4; ++r) {
                const int row = m0 + mw + i*16 + quad*4 + r;
                const int col = n0 + nw + j*16 + l16;
                const float v = acc[i][j][r] + bias[col];
                const int b = row >> 11, s = row & (S_LEN - 1);
                const int h = col >> 7,  dk = col & (DKD - 1);
                if (z < 2) {   // q/k: [B,H,S,DK]
                    unsigned short* o = ob + (size_t)z * NEL;
                    o[((size_t)(b * H_NUM + h) * S_LEN + s) * DKD + dk] = f2bf(v);
                } else {       // v: transposed [B,H,DK,S]
                    unsigned short* o = ob + 2 * NEL;
                    o[((size_t)(b * H_NUM + h) * DKD + dk) * S_LEN + s] = f2bf(v);
                }
            }
}

// ---------------- output projection: xb[4096,2048]bf16 @ wo^T + bo -> f32 ---
__launch_bounds__(256)
__global__ void gemm_out(const unsigned short* __restrict__ Ap,
                         const unsigned short* __restrict__ Bp,
                         const float* __restrict__ bias, float* __restrict__ Cg) {
    const int m0 = blockIdx.y * 128, n0 = blockIdx.x * 128;
    __shared__ __align__(16) unsigned short As[128][32];
    __shared__ __align__(16) unsigned short Bs[128][32];
    const int tid = threadIdx.x, lane = tid & 63, wave = tid >> 6;
    const int quad = lane >> 4, l16 = lane & 15;
    const int mw = (wave >> 1) * 64, nw = (wave & 1) * 64;

    floatx4 acc[4][4];
    #pragma unroll
    for (int i = 0; i < 4; ++i)
        #pragma unroll
        for (int j = 0; j < 4; ++j) acc[i][j] = (floatx4){0.f, 0.f, 0.f, 0.f};

    for (int k0 = 0; k0 < D_DIM; k0 += 32) {
        if (k0 > 0) __syncthreads();
        stage_lds_bf16(Bp, D_DIM, n0, k0, &Bs[0][0], tid);
        stage_lds_bf16(Ap, D_DIM, m0, k0, &As[0][0], tid);
        __syncthreads();
        short8 af[4], bf[4];
        #pragma unroll
        for (int i = 0; i < 4; ++i) af[i] = *(const short8*)&As[mw + i*16 + l16][quad*8];
        #pragma unroll
        for (int j = 0; j < 4; ++j) bf[j] = *(const short8*)&Bs[nw + j*16 + l16][quad*8];
        #pragma unroll
        for (int i = 0; i < 4; ++i)
            #pragma unroll
            for (int j = 0; j < 4; ++j)
                acc[i][j] = __builtin_amdgcn_mfma_f32_16x16x32_bf16(
                    af[i], bf[j], acc[i][j], 0, 0, 0);
    }
    #pragma unroll
    for (int i = 0; i < 4; ++i)
        #pragma unroll
        for (int j = 0; j < 4; ++j)
            #pragma unroll
            for (int r = 0; r < 4; ++r) {
                const int row = m0 + mw + i*16 + quad*4 + r;
                const int col = n0 + nw + j*16 + l16;
                Cg[(size_t)row * D_DIM + col] = acc[i][j][r] + bias[col];
            }
}

// ---------------- scores: exp(q@k^T * scale) masked, + atomic row sums ------
// Triangular grid: blockIdx.x in [0,136) decodes to (mt,nt), nt <= mt.
__launch_bounds__(256)
__global__ void scores_exp(const unsigned short* __restrict__ qb,
                           const unsigned short* __restrict__ kb,
                           float* __restrict__ attn, float* __restrict__ sums,
                           float scale) {
    const int idx = blockIdx.x;
    int mt = (int)((sqrtf(8.f * (float)idx + 1.f) - 1.f) * 0.5f);
    while ((mt + 1) * (mt + 2) / 2 <= idx) ++mt;     // float-error fix-up
    while (mt * (mt + 1) / 2 > idx) --mt;
    const int nt = idx - mt * (mt + 1) / 2;
    const int m0 = mt * 128, n0 = nt * 128;
    const size_t z = blockIdx.z;
    const unsigned short* Ap = qb + z * (size_t)S_LEN * DKD;
    const unsigned short* Bp = kb + z * (size_t)S_LEN * DKD;

    __shared__ __align__(16) unsigned short As[4][128][32];   // full K=128
    __shared__ __align__(16) unsigned short Bs[4][128][32];
    const int tid = threadIdx.x, lane = tid & 63, wave = tid >> 6;
    const int quad = lane >> 4, l16 = lane & 15;
    const int mw = (wave >> 1) * 64, nw = (wave & 1) * 64;

    #pragma unroll
    for (int kk = 0; kk < 4; ++kk) {
        stage_lds_bf16(Ap, DKD, m0, kk * 32, &As[kk][0][0], tid);
        stage_lds_bf16(Bp, DKD, n0, kk * 32, &Bs[kk][0][0], tid);
    }
    __syncthreads();                           // single barrier for whole K

    floatx4 acc[4][4];
    #pragma unroll
    for (int i = 0; i < 4; ++i)
        #pragma unroll
        for (int j = 0; j < 4; ++j) acc[i][j] = (floatx4){0.f, 0.f, 0.f, 0.f};

    #pragma unroll
    for (int kk = 0; kk < 4; ++kk) {
        short8 af[4], bf[4];
        #pragma unroll
        for (int i = 0; i < 4; ++i) af[i] = *(const short8*)&As[kk][mw + i*16 + l16][quad*8];
        #pragma unroll
        for (int j = 0; j < 4; ++j) bf[j] = *(const short8*)&Bs[kk][nw + j*16 + l16][quad*8];
        #pragma unroll
        for (int i = 0; i < 4; ++i)
            #pragma unroll
            for (int j = 0; j < 4; ++j)
                acc[i][j] = __builtin_amdgcn_mfma_f32_16x16x32_bf16(
                    af[i], bf[j], acc[i][j], 0, 0, 0);
    }

    float* o  = attn + z * (size_t)S_LEN * S_LEN;
    float* sm = sums + z * S_LEN;
    #pragma unroll
    for (int i = 0; i < 4; ++i)
        #pragma unroll
        for (int r = 0; r < 4; ++r) {
            const int row = m0 + mw + i*16 + quad*4 + r;
            float rsum = 0.f;
            #pragma unroll
            for (int j = 0; j < 4; ++j) {
                const int col = n0 + nw + j*16 + l16;
                const float e = (col <= row) ? __expf(acc[i][j][r] * scale) : 0.f;
                o[(size_t)row * S_LEN + col] = e;
                rsum += e;
            }
            rsum += __shfl_xor(rsum, 1, 64);   // reduce over 16 cols (l16)
            rsum += __shfl_xor(rsum, 2, 64);
            rsum += __shfl_xor(rsum, 4, 64);
            rsum += __shfl_xor(rsum, 8, 64);
            if (l16 == 0) atomicAdd(&sm[row], rsum);
        }
}

// ---------------- PV: normalize attn in place, zero-fill, P@V -> xb ---------
__launch_bounds__(256)
__global__ void pv_norm(float* __restrict__ attn,
                        const unsigned short* __restrict__ vT,
                        const float* __restrict__ sums,
                        unsigned short* __restrict__ xb) {
    const int mt = (int)gridDim.y - 1 - (int)blockIdx.y;   // long blocks first
    const int m0 = mt * 128;
    const size_t z = blockIdx.z;
    float* Sp = attn + z * (size_t)S_LEN * S_LEN;
    const unsigned short* Bp = vT + z * (size_t)DKD * S_LEN;
    const int kEnd = m0 + 128;

    __shared__ __align__(16) unsigned short As[128][32];
    __shared__ __align__(16) unsigned short Bs[128][32];
    __shared__ float inv[128];
    const int tid = threadIdx.x, lane = tid & 63, wave = tid >> 6;
    const int quad = lane >> 4, l16 = lane & 15;
    const int mw = (wave >> 1) * 64, nw = (wave & 1) * 64;

    if (tid < 128) inv[tid] = 1.f / sums[z * S_LEN + m0 + tid];
    __syncthreads();

    floatx4 acc[4][4];
    #pragma unroll
    for (int i = 0; i < 4; ++i)
        #pragma unroll
        for (int j = 0; j < 4; ++j) acc[i][j] = (floatx4){0.f, 0.f, 0.f, 0.f};

    for (int k0 = 0; k0 < kEnd; k0 += 32) {
        if (k0 > 0) __syncthreads();
        stage_lds_bf16(Bp, S_LEN, 0, k0, &Bs[0][0], tid);    // V tile (async)
        // A: read exp, normalize, write back attn, stage bf16 to LDS
        #pragma unroll
        for (int i2 = 0; i2 < 4; ++i2) {
            const int c = tid + i2 * 256;
            const int r = c >> 3, kc = (c & 7) * 4;
            float* p = Sp + (size_t)(m0 + r) * S_LEN + k0 + kc;
            floatx4 v = *(const floatx4*)p;
            const float iv = inv[r];
            floatx4 w;
            w[0] = v[0] * iv; w[1] = v[1] * iv; w[2] = v[2] * iv; w[3] = v[3] * iv;
            *(floatx4*)p = w;
            short4v pk;
            pk[0] = (short)f2bf(w[0]); pk[1] = (short)f2bf(w[1]);
            pk[2] = (short)f2bf(w[2]); pk[3] = (short)f2bf(w[3]);
            *(short4v*)(&As[r][kc]) = pk;
        }
        __syncthreads();
        short8 af[4], bf[4];
        #pragma unroll
        for (int i = 0; i < 4; ++i) af[i] = *(const short8*)&As[mw + i*16 + l16][quad*8];
        #pragma unroll
        for (int j = 0; j < 4; ++j) bf[j] = *(const short8*)&Bs[nw + j*16 + l16][quad*8];
        #pragma unroll
        for (int i = 0; i < 4; ++i)
            #pragma unroll
            for (int j = 0; j < 4; ++j)
                acc[i][j] = __builtin_amdgcn_mfma_f32_16x16x32_bf16(
                    af[i], bf[j], acc[i][j], 0, 0, 0);
    }

    // epilogue: xb [B,S,D] bf16
    const int b = (int)(z >> 4), h = (int)(z & 15);
    #pragma unroll
    for (int i = 0; i < 4; ++i)
        #pragma unroll
        for (int j = 0; j < 4; ++j)
            #pragma unroll
            for (int r = 0; r < 4; ++r) {
                const int row = m0 + mw + i*16 + quad*4 + r;
                const int col = nw + j*16 + l16;
                xb[((size_t)(b * S_LEN + row)) * D_DIM + h * DKD + col] =
                    f2bf(acc[i][j][r]);
            }

    // zero-fill masked upper region: rows m0..m0+127, cols kEnd..2047
    const int width = S_LEN - kEnd;
    if (width > 0) {
        const floatx4 z4 = {0.f, 0.f, 0.f, 0.f};
        for (int r = 0; r < 128; ++r) {
            float* rp = Sp + (size_t)(m0 + r) * S_LEN + kEnd;
            for (int c = tid * 4; c < width; c += 1024)
                *(floatx4*)(rp + c) = z4;
        }
    }
}

// ---------------- fp32 -> bf16 converts (fused: 3 inputs / 4 weights) -------
__launch_bounds__(256)
__global__ void cvt3(const float* __restrict__ a, const float* __restrict__ b,
                     const float* __restrict__ c, unsigned short* __restrict__ dst,
                     size_t stride) {
    const float* src = (blockIdx.y == 0) ? a : (blockIdx.y == 1) ? b : c;
    const size_t i = ((size_t)blockIdx.x * 256 + threadIdx.x) * 8;
    const floatx4 x = *(const floatx4*)(src + i);
    const floatx4 y = *(const floatx4*)(src + i + 4);
    short8 o;
    o[0] = (short)f2bf(x[0]); o[1] = (short)f2bf(x[1]);
    o[2] = (short)f2bf(x[2]); o[3] = (short)f2bf(x[3]);
    o[4] = (short)f2bf(y[0]); o[5] = (short)f2bf(y[1]);
    o[6] = (short)f2bf(y[2]); o[7] = (short)f2bf(y[3]);
    *(short8*)(dst + blockIdx.y * stride + i) = o;
}

__launch_bounds__(256)
__global__ void cvt4(const float* __restrict__ a, const float* __restrict__ b,
                     const float* __restrict__ c, const float* __restrict__ d,
                     unsigned short* __restrict__ dst, size_t stride) {
    const float* src = (blockIdx.y == 0) ? a : (blockIdx.y == 1) ? b
                     : (blockIdx.y == 2) ? c : d;
    const size_t i = ((size_t)blockIdx.x * 256 + threadIdx.x) * 8;
    const floatx4 x = *(const floatx4*)(src + i);
    const floatx4 y = *(const floatx4*)(src + i + 4);
    short8 o;
    o[0] = (short)f2bf(x[0]); o[1] = (short)f2bf(x[1]);
    o[2] = (short)f2bf(x[2]); o[3] = (short)f2bf(x[3]);
    o[4] = (short)f2bf(y[0]); o[5] = (short)f2bf(y[1]);
    o[6] = (short)f2bf(y[2]); o[7] = (short)f2bf(y[3]);
    *(short8*)(dst + blockIdx.y * stride + i) = o;
}

__launch_bounds__(256)
__global__ void zero_sums(float* __restrict__ sums) {
    const size_t i = ((size_t)blockIdx.x * 256 + threadIdx.x) * 4;
    *(floatx4*)(sums + i) = (floatx4){0.f, 0.f, 0.f, 0.f};
}

extern "C" void kernel_launch(void* const* d_in, const int* in_sizes, int n_in,
                              void* d_out, int out_size, void* d_ws, size_t ws_size,
                              hipStream_t stream) {
    const float* query = (const float*)d_in[0];
    const float* key_  = (const float*)d_in[1];
    const float* value = (const float*)d_in[2];
    const float* Wq = (const float*)d_in[3];
    const float* bq = (const float*)d_in[4];
    const float* Wk = (const float*)d_in[5];
    const float* bk = (const float*)d_in[6];
    const float* Wv = (const float*)d_in[7];
    const float* bv = (const float*)d_in[8];
    const float* Wo = (const float*)d_in[9];
    const float* bo = (const float*)d_in[10];

    float* out  = (float*)d_out;
    float* attn = out + NEL;

    unsigned short* qb = (unsigned short*)d_ws;          // [B,H,S,DK]
    unsigned short* kb = qb + NEL;
    unsigned short* vT = kb + NEL;                       // [B,H,DK,S]
    unsigned short* xb = vT + NEL;                       // [B,S,D]
    unsigned short* qf = xb + NEL;                       // converted inputs
    unsigned short* wq = qf + 3 * NEL;                   // converted weights
    unsigned short* wo = wq + 3 * NWL;
    float* sums = (float*)(wo + NWL);                    // [B*H*S] f32

    const dim3 blk(256);
    const float iscale = 0.088388347648318447f;          // 1/sqrt(128)

    // converts + sum zeroing
    cvt3<<<dim3(NEL / 2048, 3), blk, 0, stream>>>(query, key_, value, qf, NEL);
    cvt4<<<dim3(NWL / 2048, 4), blk, 0, stream>>>(Wq, Wk, Wv, Wo, wq, NWL);
    zero_sums<<<dim3((BATCH * H_NUM * S_LEN) / 1024), blk, 0, stream>>>(sums);

    // fused QKV projections (z = 0:q, 1:k, 2:v)
    proj_qkv<<<dim3(D_DIM / 128, (BATCH * S_LEN) / 128, 3), blk, 0, stream>>>(
        qf, wq, bq, bk, bv, qb);

    // scores: exp(q@k^T/sqrt(dk)) masked, atomic row sums; triangular grid
    scores_exp<<<dim3(136, 1, BATCH * H_NUM), blk, 0, stream>>>(
        qb, kb, attn, sums, iscale);

    // PV: normalize attn in place + zero-fill upper + P@V
    pv_norm<<<dim3(1, S_LEN / 128, BATCH * H_NUM), blk, 0, stream>>>(
        attn, vT, sums, xb);

    // output projection
    gemm_out<<<dim3(D_DIM / 128, (BATCH * S_LEN) / 128), blk, 0, stream>>>(
        xb, wq + 3 * NWL, bo, out);
}

// Round 4
// 1098.519 us; speedup vs baseline: 1.1256x; 1.1256x over previous
//
#include <hip/hip_runtime.h>

// Causal self-attention, B=2 S=2048 D=2048 H=16 DK=128.
// d_out = [out: 4096*2048 f32][attn: 2*16*2048*2048 f32]
// ws (bf16): qb,kb [B,H,S,DK], vT [B,H,DK,S], xb [B,S,D], qf,kf,vf [B,S,D],
//            wq,wk,wv,wo [D,D].
// Pipeline (5 launches): cvt3, cvt4 -> fused QKV proj -> attn_fused
//   (QK^T + exp + row-sums + PV + normalized-attn write, flash-style) -> out proj.
// No max-subtraction (S*iscale ~ N(0,1); overflow needs ~88 sigma).

#define BATCH 2
#define S_LEN 2048
#define D_DIM 2048
#define H_NUM 16
#define DKD   128
#define QBLK  32
#define NEL   ((size_t)BATCH * S_LEN * D_DIM)   // 8388608
#define NWL   ((size_t)D_DIM * D_DIM)           // 4194304

typedef __attribute__((ext_vector_type(8))) short  short8;
typedef __attribute__((ext_vector_type(4))) short  short4v;
typedef __attribute__((ext_vector_type(4))) float  floatx4;

__device__ __forceinline__ unsigned short f2bf(float f) {
    unsigned int u = __float_as_uint(f);
    u += 0x7fffu + ((u >> 16) & 1u);   // round-to-nearest-even
    return (unsigned short)(u >> 16);
}

__device__ __forceinline__ void gload16(const void* g, void* l) {
    __builtin_amdgcn_global_load_lds(
        (const __attribute__((address_space(1))) void*)g,
        (__attribute__((address_space(3))) void*)l, 16, 0, 0);
}

// 128(row) x 32(k) bf16 tile -> LDS [128][32] via global_load_lds width=16.
__device__ __forceinline__ void stage_lds_bf16(const unsigned short* __restrict__ src,
                                               int ld, int row0, int k0,
                                               unsigned short* __restrict__ dst,
                                               int tid) {
    #pragma unroll
    for (int j = 0; j < 2; ++j) {
        const int c = tid + j * 256;          // 512 chunks of 8 bf16 (16 B)
        const int r = c >> 2, kc = (c & 3) * 8;
        gload16(src + (size_t)(row0 + r) * ld + k0 + kc, dst + c * 8);
    }
}

// ---------------- fused QKV projection: z in {0,1,2} selects q/k/v ----------
__launch_bounds__(256)
__global__ void proj_qkv(const unsigned short* __restrict__ xf,
                         const unsigned short* __restrict__ wb,
                         const float* __restrict__ bq, const float* __restrict__ bk,
                         const float* __restrict__ bv,
                         unsigned short* __restrict__ ob) {
    const int z = blockIdx.z;
    const unsigned short* Ap = xf + (size_t)z * NEL;
    const unsigned short* Bp = wb + (size_t)z * NWL;
    const float* bias = (z == 0) ? bq : (z == 1) ? bk : bv;
    const int m0 = blockIdx.y * 128, n0 = blockIdx.x * 128;

    __shared__ __align__(16) unsigned short As[128][32];
    __shared__ __align__(16) unsigned short Bs[128][32];
    const int tid = threadIdx.x, lane = tid & 63, wave = tid >> 6;
    const int quad = lane >> 4, l16 = lane & 15;
    const int mw = (wave >> 1) * 64, nw = (wave & 1) * 64;

    floatx4 acc[4][4];
    #pragma unroll
    for (int i = 0; i < 4; ++i)
        #pragma unroll
        for (int j = 0; j < 4; ++j) acc[i][j] = (floatx4){0.f, 0.f, 0.f, 0.f};

    for (int k0 = 0; k0 < D_DIM; k0 += 32) {
        if (k0 > 0) __syncthreads();
        stage_lds_bf16(Bp, D_DIM, n0, k0, &Bs[0][0], tid);
        stage_lds_bf16(Ap, D_DIM, m0, k0, &As[0][0], tid);
        __syncthreads();
        short8 af[4], bf[4];
        #pragma unroll
        for (int i = 0; i < 4; ++i) af[i] = *(const short8*)&As[mw + i*16 + l16][quad*8];
        #pragma unroll
        for (int j = 0; j < 4; ++j) bf[j] = *(const short8*)&Bs[nw + j*16 + l16][quad*8];
        #pragma unroll
        for (int i = 0; i < 4; ++i)
            #pragma unroll
            for (int j = 0; j < 4; ++j)
                acc[i][j] = __builtin_amdgcn_mfma_f32_16x16x32_bf16(
                    af[i], bf[j], acc[i][j], 0, 0, 0);
    }

    #pragma unroll
    for (int i = 0; i < 4; ++i)
        #pragma unroll
        for (int j = 0; j < 4; ++j)
            #pragma unroll
            for (int r = 0; r < 4; ++r) {
                const int row = m0 + mw + i*16 + quad*4 + r;
                const int col = n0 + nw + j*16 + l16;
                const float v = acc[i][j][r] + bias[col];
                const int b = row >> 11, s = row & (S_LEN - 1);
                const int h = col >> 7,  dk = col & (DKD - 1);
                if (z < 2) {   // q/k: [B,H,S,DK]
                    unsigned short* o = ob + (size_t)z * NEL;
                    o[((size_t)(b * H_NUM + h) * S_LEN + s) * DKD + dk] = f2bf(v);
                } else {       // v: transposed [B,H,DK,S]
                    unsigned short* o = ob + 2 * NEL;
                    o[((size_t)(b * H_NUM + h) * DKD + dk) * S_LEN + s] = f2bf(v);
                }
            }
}

// ---------------- output projection ----------------------------------------
__launch_bounds__(256)
__global__ void gemm_out(const unsigned short* __restrict__ Ap,
                         const unsigned short* __restrict__ Bp,
                         const float* __restrict__ bias, float* __restrict__ Cg) {
    const int m0 = blockIdx.y * 128, n0 = blockIdx.x * 128;
    __shared__ __align__(16) unsigned short As[128][32];
    __shared__ __align__(16) unsigned short Bs[128][32];
    const int tid = threadIdx.x, lane = tid & 63, wave = tid >> 6;
    const int quad = lane >> 4, l16 = lane & 15;
    const int mw = (wave >> 1) * 64, nw = (wave & 1) * 64;

    floatx4 acc[4][4];
    #pragma unroll
    for (int i = 0; i < 4; ++i)
        #pragma unroll
        for (int j = 0; j < 4; ++j) acc[i][j] = (floatx4){0.f, 0.f, 0.f, 0.f};

    for (int k0 = 0; k0 < D_DIM; k0 += 32) {
        if (k0 > 0) __syncthreads();
        stage_lds_bf16(Bp, D_DIM, n0, k0, &Bs[0][0], tid);
        stage_lds_bf16(Ap, D_DIM, m0, k0, &As[0][0], tid);
        __syncthreads();
        short8 af[4], bf[4];
        #pragma unroll
        for (int i = 0; i < 4; ++i) af[i] = *(const short8*)&As[mw + i*16 + l16][quad*8];
        #pragma unroll
        for (int j = 0; j < 4; ++j) bf[j] = *(const short8*)&Bs[nw + j*16 + l16][quad*8];
        #pragma unroll
        for (int i = 0; i < 4; ++i)
            #pragma unroll
            for (int j = 0; j < 4; ++j)
                acc[i][j] = __builtin_amdgcn_mfma_f32_16x16x32_bf16(
                    af[i], bf[j], acc[i][j], 0, 0, 0);
    }
    #pragma unroll
    for (int i = 0; i < 4; ++i)
        #pragma unroll
        for (int j = 0; j < 4; ++j)
            #pragma unroll
            for (int r = 0; r < 4; ++r) {
                const int row = m0 + mw + i*16 + quad*4 + r;
                const int col = n0 + nw + j*16 + l16;
                Cg[(size_t)row * D_DIM + col] = acc[i][j][r] + bias[col];
            }
}

// ---------------- fused attention: QK^T + exp + sums + PV + attn write ------
// One block = 32 q-rows of one (b,h). 4 waves; wave w owns cols w*32..w*32+31
// of both S (k-cols per tile) and the PV output (dk-cols).
__launch_bounds__(256)
__global__ void attn_fused(const unsigned short* __restrict__ qb,
                           const unsigned short* __restrict__ kb,
                           const unsigned short* __restrict__ vTg,
                           float* __restrict__ attn,
                           unsigned short* __restrict__ xb,
                           float iscale) {
    const int bid = blockIdx.x;
    // XCD-cluster swizzle: each XCD (bid&7) sees 4 heads; longest tiles first.
    const int z  = ((bid & 7) << 2) | ((bid >> 3) & 3);
    const int mt = 63 - (bid >> 5);
    const int m0 = mt * QBLK;
    const int nkt = (m0 + QBLK + 127) >> 7;       // 128-col K-tiles
    const unsigned short* qz = qb  + (size_t)z * S_LEN * DKD;
    const unsigned short* kz = kb  + (size_t)z * S_LEN * DKD;
    const unsigned short* vz = vTg + (size_t)z * DKD * S_LEN;
    float* az = attn + (size_t)z * S_LEN * S_LEN;

    __shared__ __align__(16) unsigned short Ks[4][128][32];   // 32 KB
    __shared__ __align__(16) unsigned short Vs[4][128][32];   // 32 KB
    __shared__ __align__(16) unsigned short Ps[4][QBLK][32];  // 8 KB
    __shared__ float rsum[QBLK];

    const int tid = threadIdx.x, lane = tid & 63, w = tid >> 6;
    const int quad = lane >> 4, l16 = lane & 15;

    if (tid < QBLK) rsum[tid] = 0.f;

    // Q fragments in registers for the whole block (L2-warm from proj).
    short8 afq[2][4];
    #pragma unroll
    for (int i = 0; i < 2; ++i)
        #pragma unroll
        for (int kk = 0; kk < 4; ++kk)
            afq[i][kk] = *(const short8*)(qz + (size_t)(m0 + i*16 + l16) * DKD
                                             + kk*32 + quad*8);

    floatx4 acc_pv[2][2];
    #pragma unroll
    for (int i = 0; i < 2; ++i)
        #pragma unroll
        for (int jj = 0; jj < 2; ++jj) acc_pv[i][jj] = (floatx4){0.f,0.f,0.f,0.f};
    float rp[2][4];
    #pragma unroll
    for (int i = 0; i < 2; ++i)
        #pragma unroll
        for (int r = 0; r < 4; ++r) rp[i][r] = 0.f;

    for (int kt = 0; kt < nkt; ++kt) {
        const int k0 = kt * 128;
        if (kt > 0) __syncthreads();              // Ks/Vs/Ps reuse
        #pragma unroll
        for (int kk = 0; kk < 4; ++kk) {
            stage_lds_bf16(kz, DKD,   k0, kk*32,      &Ks[kk][0][0], tid);
            stage_lds_bf16(vz, S_LEN, 0,  k0 + kk*32, &Vs[kk][0][0], tid);
        }
        __syncthreads();

        // S = q @ k^T for this 32x128 tile
        floatx4 acc_s[2][2];
        #pragma unroll
        for (int i = 0; i < 2; ++i)
            #pragma unroll
            for (int jj = 0; jj < 2; ++jj) acc_s[i][jj] = (floatx4){0.f,0.f,0.f,0.f};
        #pragma unroll
        for (int kk = 0; kk < 4; ++kk)
            #pragma unroll
            for (int jj = 0; jj < 2; ++jj) {
                const short8 bfk = *(const short8*)&Ks[kk][w*32 + jj*16 + l16][quad*8];
                #pragma unroll
                for (int i = 0; i < 2; ++i)
                    acc_s[i][jj] = __builtin_amdgcn_mfma_f32_16x16x32_bf16(
                        afq[i][kk], bfk, acc_s[i][jj], 0, 0, 0);
            }

        // exp + mask + unnormalized e-write + partial sums + P->LDS
        #pragma unroll
        for (int i = 0; i < 2; ++i)
            #pragma unroll
            for (int jj = 0; jj < 2; ++jj)
                #pragma unroll
                for (int r = 0; r < 4; ++r) {
                    const int row = m0 + i*16 + quad*4 + r;
                    const int col = k0 + w*32 + jj*16 + l16;
                    const float e = (col <= row)
                        ? __expf(acc_s[i][jj][r] * iscale) : 0.f;
                    az[(size_t)row * S_LEN + col] = e;
                    rp[i][r] += e;
                    Ps[w][i*16 + quad*4 + r][jj*16 + l16] = f2bf(e);
                }
        __syncthreads();

        // PV accumulate: acc_pv += P @ V (V^T rows from vT layout)
        #pragma unroll
        for (int kk = 0; kk < 4; ++kk) {
            short8 afp[2], bfv[2];
            #pragma unroll
            for (int i = 0; i < 2; ++i)
                afp[i] = *(const short8*)&Ps[kk][i*16 + l16][quad*8];
            #pragma unroll
            for (int jj = 0; jj < 2; ++jj)
                bfv[jj] = *(const short8*)&Vs[kk][w*32 + jj*16 + l16][quad*8];
            #pragma unroll
            for (int i = 0; i < 2; ++i)
                #pragma unroll
                for (int jj = 0; jj < 2; ++jj)
                    acc_pv[i][jj] = __builtin_amdgcn_mfma_f32_16x16x32_bf16(
                        afp[i], bfv[jj], acc_pv[i][jj], 0, 0, 0);
        }
    }

    // row-sum reduce: over l16 lanes in-wave, then across waves via LDS
    #pragma unroll
    for (int i = 0; i < 2; ++i)
        #pragma unroll
        for (int r = 0; r < 4; ++r) {
            float v = rp[i][r];
            v += __shfl_xor(v, 1, 64); v += __shfl_xor(v, 2, 64);
            v += __shfl_xor(v, 4, 64); v += __shfl_xor(v, 8, 64);
            if (l16 == 0) atomicAdd(&rsum[i*16 + quad*4 + r], v);
        }
    __syncthreads();   // also drains this wave's e-stores (vmcnt) pre-readback

    // xb = (e @ V) * inv  (normalization is a row scalar)
    const int b = z >> 4, h = z & 15;
    #pragma unroll
    for (int i = 0; i < 2; ++i)
        #pragma unroll
        for (int jj = 0; jj < 2; ++jj)
            #pragma unroll
            for (int r = 0; r < 4; ++r) {
                const int row = i*16 + quad*4 + r;
                const float inv = 1.f / rsum[row];
                xb[((size_t)(b * S_LEN + m0 + row)) * D_DIM
                   + h*DKD + w*32 + jj*16 + l16] = f2bf(acc_pv[i][jj][r] * inv);
            }

    // normalize e rows in attn (L2-warm readback) + zero-fill masked tail
    const int ncols4 = nkt * 32;          // floatx4 units holding e
    for (int r = 0; r < QBLK; ++r) {
        const float inv = 1.f / rsum[r];
        float* rowp = az + (size_t)(m0 + r) * S_LEN;
        for (int c = tid; c < ncols4; c += 256) {
            floatx4 v = *(const floatx4*)(rowp + c*4);
            v[0] *= inv; v[1] *= inv; v[2] *= inv; v[3] *= inv;
            *(floatx4*)(rowp + c*4) = v;
        }
        for (int c = ncols4 + tid; c < S_LEN/4; c += 256)
            *(floatx4*)(rowp + c*4) = (floatx4){0.f,0.f,0.f,0.f};
    }
}

// ---------------- fp32 -> bf16 converts -------------------------------------
__launch_bounds__(256)
__global__ void cvt3(const float* __restrict__ a, const float* __restrict__ b,
                     const float* __restrict__ c, unsigned short* __restrict__ dst,
                     size_t stride) {
    const float* src = (blockIdx.y == 0) ? a : (blockIdx.y == 1) ? b : c;
    const size_t i = ((size_t)blockIdx.x * 256 + threadIdx.x) * 8;
    const floatx4 x = *(const floatx4*)(src + i);
    const floatx4 y = *(const floatx4*)(src + i + 4);
    short8 o;
    o[0] = (short)f2bf(x[0]); o[1] = (short)f2bf(x[1]);
    o[2] = (short)f2bf(x[2]); o[3] = (short)f2bf(x[3]);
    o[4] = (short)f2bf(y[0]); o[5] = (short)f2bf(y[1]);
    o[6] = (short)f2bf(y[2]); o[7] = (short)f2bf(y[3]);
    *(short8*)(dst + blockIdx.y * stride + i) = o;
}

__launch_bounds__(256)
__global__ void cvt4(const float* __restrict__ a, const float* __restrict__ b,
                     const float* __restrict__ c, const float* __restrict__ d,
                     unsigned short* __restrict__ dst, size_t stride) {
    const float* src = (blockIdx.y == 0) ? a : (blockIdx.y == 1) ? b
                     : (blockIdx.y == 2) ? c : d;
    const size_t i = ((size_t)blockIdx.x * 256 + threadIdx.x) * 8;
    const floatx4 x = *(const floatx4*)(src + i);
    const floatx4 y = *(const floatx4*)(src + i + 4);
    short8 o;
    o[0] = (short)f2bf(x[0]); o[1] = (short)f2bf(x[1]);
    o[2] = (short)f2bf(x[2]); o[3] = (short)f2bf(x[3]);
    o[4] = (short)f2bf(y[0]); o[5] = (short)f2bf(y[1]);
    o[6] = (short)f2bf(y[2]); o[7] = (short)f2bf(y[3]);
    *(short8*)(dst + blockIdx.y * stride + i) = o;
}

extern "C" void kernel_launch(void* const* d_in, const int* in_sizes, int n_in,
                              void* d_out, int out_size, void* d_ws, size_t ws_size,
                              hipStream_t stream) {
    const float* query = (const float*)d_in[0];
    const float* key_  = (const float*)d_in[1];
    const float* value = (const float*)d_in[2];
    const float* Wq = (const float*)d_in[3];
    const float* bq = (const float*)d_in[4];
    const float* Wk = (const float*)d_in[5];
    const float* bk = (const float*)d_in[6];
    const float* Wv = (const float*)d_in[7];
    const float* bv = (const float*)d_in[8];
    const float* Wo = (const float*)d_in[9];
    const float* bo = (const float*)d_in[10];

    float* out  = (float*)d_out;
    float* attn = out + NEL;

    unsigned short* qb = (unsigned short*)d_ws;          // [B,H,S,DK]
    unsigned short* kb = qb + NEL;
    unsigned short* vT = kb + NEL;                       // [B,H,DK,S]
    unsigned short* xb = vT + NEL;                       // [B,S,D]
    unsigned short* qf = xb + NEL;                       // converted inputs
    unsigned short* wq = qf + 3 * NEL;                   // converted weights
    unsigned short* wo = wq + 3 * NWL;

    const dim3 blk(256);
    const float iscale = 0.088388347648318447f;          // 1/sqrt(128)

    cvt3<<<dim3(NEL / 2048, 3), blk, 0, stream>>>(query, key_, value, qf, NEL);
    cvt4<<<dim3(NWL / 2048, 4), blk, 0, stream>>>(Wq, Wk, Wv, Wo, wq, NWL);

    proj_qkv<<<dim3(D_DIM / 128, (BATCH * S_LEN) / 128, 3), blk, 0, stream>>>(
        qf, wq, bq, bk, bv, qb);

    attn_fused<<<dim3(BATCH * H_NUM * (S_LEN / QBLK)), blk, 0, stream>>>(
        qb, kb, vT, attn, xb, iscale);

    gemm_out<<<dim3(D_DIM / 128, (BATCH * S_LEN) / 128), blk, 0, stream>>>(
        xb, wo, bo, out);
}